// Round 15
// baseline (167.314 us; speedup 1.0000x reference)
//
#include <hip/hip_runtime.h>
#include <hip/hip_bf16.h>
#include <stdint.h>

#define B_   64
#define L_   4096
#define H_   128
#define T_   64
#define C_   (L_/T_)        // 64 chunks per batch row
#define BH_  (B_*H_)        // 8192
#define PADI 136            // bf16 row stride for inp tile

typedef __attribute__((ext_vector_type(8))) short short8;
typedef __attribute__((ext_vector_type(4))) short short4v;
typedef __attribute__((ext_vector_type(4))) float floatx4;
typedef __attribute__((ext_vector_type(2))) float floatx2;

#define LOG2E 1.44269504088896340736f

__device__ __forceinline__ unsigned short f2bf(float f){
    unsigned int u = __float_as_uint(f);
    u += 0x7FFFu + ((u >> 16) & 1u);      // RNE
    return (unsigned short)(u >> 16);
}
__device__ __forceinline__ float bf2f(unsigned short s){
    return __uint_as_float(((unsigned int)s) << 16);
}

// K0: W^T bf16 prep (dense [n][k]); 32 blocks.
__global__ void prep_w(const float* __restrict__ Wz, const float* __restrict__ Wh,
                       unsigned short* __restrict__ WzT, unsigned short* __restrict__ WhT){
    int b = blockIdx.x;
    const float* W = (b < 16) ? Wz : Wh;
    unsigned short* WT = (b < 16) ? WzT : WhT;
    int b16 = b & 15, tid = threadIdx.x;
    #pragma unroll
    for (int it = 0; it < 4; ++it){
        int idx = b16*1024 + it*256 + tid;    // idx = n*128 + k
        int n = idx >> 7, k = idx & 127;
        WT[idx] = f2bf(W[k*H_ + n]);
    }
}

// ab LDS layout: row col (0..127) of 256B; 16B chunk t4 at position t4^(col&15).
// Pair (a,b) for t = t4*4+e at ushorts [chunk*8 + 2e, +1]. After the scan the
// pair holds (hw, pw) = (hloc_{t-1}*wg, P(t)*wg) in the same slots.

// Pass 1 (exact r12 best): inp + fused dual GEMM + trimmed gate epilogue +
// LDS in-place scan + coalesced pw dump + conflict-free sloc reduction.
__global__ __launch_bounds__(256, 4)
void gates_agg(const float* __restrict__ x,
               const float* __restrict__ Wp, const float* __restrict__ bp,
               const float* __restrict__ bz, const float* __restrict__ bh,
               const float* __restrict__ Wg,
               const unsigned short* __restrict__ WzT,
               const unsigned short* __restrict__ WhT,
               floatx2* __restrict__ agg2,
               float* __restrict__ sloc, unsigned short* __restrict__ pw_g)
{
    __shared__ __align__(16) unsigned short s_ab[H_*H_];    // 32 KB (inp overlays)
    __shared__ float s_bz[H_], s_bh[H_], s_wg[H_];
    __shared__ float s_part[256];
    unsigned short* inp_lds = s_ab;

    const int bid = blockIdx.x;
    const int bb  = bid / C_;
    const int cc  = bid % C_;
    const int t0g = cc * T_;
    const int tid = threadIdx.x;
    const int wv = tid >> 6, lane = tid & 63, quad = lane >> 4, l15 = lane & 15;

    if (tid < H_){ s_bz[tid] = bz[tid]; s_bh[tid] = bh[tid]; s_wg[tid] = Wg[tid]; }

    // ---- inp = x @ Wp + bp -> bf16 LDS (A layout [t][k]); Wp/bp hoisted ----
    {
        const int h0 = (tid & 15) * 8;         // iteration-invariant
        float w0[8], w1[8], w2[8], b0[8];
        #pragma unroll
        for (int m = 0; m < 8; ++m){
            w0[m] = Wp[h0+m]; w1[m] = Wp[H_+h0+m]; w2[m] = Wp[2*H_+h0+m];
            b0[m] = bp[h0+m];
        }
        #pragma unroll
        for (int it = 0; it < 4; ++it){
            int t = (tid >> 4) + it*16;
            const float* xr = x + ((size_t)bb*L_ + t0g + t)*3;
            float x0 = xr[0], x1 = xr[1], x2 = xr[2];
            short8 pk;
            #pragma unroll
            for (int m = 0; m < 8; ++m){
                float v = b0[m];
                v = fmaf(x0, w0[m], v);
                v = fmaf(x1, w1[m], v);
                v = fmaf(x2, w2[m], v);
                pk[m] = (short)f2bf(v);
            }
            *(short8*)&inp_lds[t*PADI + h0] = pk;
        }
    }
    __syncthreads();

    const int ct0 = wv*2;

    // ---- fused dual GEMM: Sz/Sh = inp @ {Wz,Wh}^T, A-frags read once ----
    floatx4 accz[4][2], acch[4][2];
    #pragma unroll
    for (int r = 0; r < 4; ++r)
        #pragma unroll
        for (int c = 0; c < 2; ++c){
            accz[r][c] = (floatx4){0.f,0.f,0.f,0.f};
            acch[r][c] = (floatx4){0.f,0.f,0.f,0.f};
        }
    #pragma unroll
    for (int kk = 0; kk < 4; ++kk){
        short8 af[4], bz_[2], bh_[2];
        #pragma unroll
        for (int r = 0; r < 4; ++r)
            af[r] = *(const short8*)&inp_lds[(r*16 + l15)*PADI + kk*32 + quad*8];
        #pragma unroll
        for (int c = 0; c < 2; ++c){
            bz_[c] = *(const short8*)&WzT[((ct0+c)*16 + l15)*H_ + kk*32 + quad*8];
            bh_[c] = *(const short8*)&WhT[((ct0+c)*16 + l15)*H_ + kk*32 + quad*8];
        }
        #pragma unroll
        for (int r = 0; r < 4; ++r)
            #pragma unroll
            for (int c = 0; c < 2; ++c){
                accz[r][c] = __builtin_amdgcn_mfma_f32_16x16x32_bf16(af[r], bz_[c], accz[r][c], 0, 0, 0);
                acch[r][c] = __builtin_amdgcn_mfma_f32_16x16x32_bf16(af[r], bh_[c], acch[r][c], 0, 0, 0);
            }
    }
    __syncthreads();   // inp reads done before ab overlay

    // ---- trimmed epilogue: a = sigmoid(-sz); b = (1-a)*tanh(sh) ----
    #pragma unroll
    for (int r = 0; r < 4; ++r){
        #pragma unroll
        for (int c = 0; c < 2; ++c){
            int col = (ct0+c)*16 + l15;
            float vbz = s_bz[col], vbh = s_bh[col];
            short8 pk;
            #pragma unroll
            for (int e = 0; e < 4; ++e){
                float szb = accz[r][c][e] + vbz;
                float a = __builtin_amdgcn_rcpf(1.0f + __builtin_amdgcn_exp2f(szb * LOG2E));
                float shb = acch[r][c][e] + vbh;
                float ex = __builtin_amdgcn_exp2f(2.0f*LOG2E*shb);
                float th = 1.0f - 2.0f*__builtin_amdgcn_rcpf(ex + 1.0f);
                float bt = (1.0f - a) * th;
                pk[2*e]   = (short)f2bf(a);
                pk[2*e+1] = (short)f2bf(bt);
            }
            int ch = (r*4 + quad) ^ l15;
            *(short8*)&s_ab[col*H_ + ch*8] = pk;
        }
    }
    __syncthreads();

    // ---- LDS-only in-place scan: (a,b) -> (hw,pw); agg out (float2) ----
    if (tid < H_){
        float A = 1.0f, h = 0.0f;
        float wgv = s_wg[tid];
        #pragma unroll
        for (int t4 = 0; t4 < 16; ++t4){
            int base = tid*H_ + ((t4 ^ (tid & 15)) << 3);
            short8 pr = *(const short8*)&s_ab[base];
            short8 wb;
            #pragma unroll
            for (int e = 0; e < 4; ++e){
                float aa = bf2f((unsigned short)pr[2*e]);
                float bv = bf2f((unsigned short)pr[2*e+1]);
                wb[2*e]   = (short)f2bf(h * wgv);   // hloc_{t-1} * wg
                wb[2*e+1] = (short)f2bf(A * wgv);   // P(t) * wg
                A *= aa;
                h = fmaf(aa, h, bv);
            }
            *(short8*)&s_ab[base] = wb;             // in-place, same banks
        }
        agg2[(size_t)(bb*H_ + tid)*C_ + cc] = (floatx2){A, h};
    }
    __syncthreads();

    // ---- coalesced pw dump: deinterleave to [col][t], all 256 threads ----
    {
        unsigned short* dst = pw_g + (size_t)bid*(T_*H_);
        #pragma unroll
        for (int i = 0; i < 8; ++i){
            int idx = i*256 + tid;                 // (col, t4)
            int col = idx >> 4, t4 = idx & 15;
            short8 pr = *(const short8*)&s_ab[col*H_ + ((t4 ^ (col & 15)) << 3)];
            short4v pw4;
            pw4[0] = pr[1]; pw4[1] = pr[3]; pw4[2] = pr[5]; pw4[3] = pr[7];
            *(short4v*)&dst[col*T_ + t4*4] = pw4;  // consecutive 8B per thread
        }
    }

    // ---- sloc reduction, conflict-free (lane index = t) ----
    {
        int t = tid & 63, w4 = tid >> 6;
        int t4 = t >> 2, e2 = (t & 3)*2;
        float s = 0.0f;
        #pragma unroll
        for (int j = 0; j < 32; ++j){
            int col = w4*32 + j;
            s += bf2f(s_ab[col*H_ + ((t4 ^ (col & 15)) << 3) + e2]);
        }
        s_part[w4*64 + t] = s;
    }
    __syncthreads();
    if (tid < 64)
        sloc[(size_t)bid*T_ + tid] =
            s_part[tid] + s_part[64+tid] + s_part[128+tid] + s_part[192+tid];
}

// Pass 2: fused Kogge-Stone carry compose (agg2 is L2/L3-hot, 4 MB) + pw dot.
// 4 chunks per block (grid 1024). One fewer dispatch than r12.
__global__ __launch_bounds__(256, 4)
void apply2(const unsigned short* __restrict__ pw_g,
            const floatx2* __restrict__ agg2,
            const float* __restrict__ sloc, const float* __restrict__ bg,
            float* __restrict__ preds)
{
    __shared__ float s_c[4][H_];
    __shared__ float s_part[4][256];
    const int bid = blockIdx.x;          // 1024 blocks
    const int bb  = bid >> 4;
    const int cc0 = (bid & 15) * 4;
    const int tid = threadIdx.x;
    const int wv = tid >> 6, lane = tid & 63;
    const int cl = lane >> 3, t8 = lane & 7;

    // ---- fused carry compose: wave wv scans rows h = wv*32 .. wv*32+31 ----
    // lane = cc; Kogge-Stone inclusive scan, exclusive extract at cc0..cc0+3.
    // Bit-identical compose order to the standalone carry_kogge kernel.
    #pragma unroll 4
    for (int i = 0; i < 32; ++i){
        int h = wv*32 + i;
        floatx2 v = agg2[(size_t)(bb*H_ + h)*C_ + lane];
        #pragma unroll
        for (int d = 1; d < 64; d <<= 1){
            float oA = __shfl_up(v[0], d, 64);
            float oH = __shfl_up(v[1], d, 64);
            if (lane >= d){
                v[1] = fmaf(oH, v[0], v[1]);
                v[0] = oA * v[0];
            }
        }
        float eh = __shfl_up(v[1], 1, 64);
        if ((unsigned)(lane - cc0) < 4u)
            s_c[lane - cc0][h] = (lane == 0) ? 0.0f : eh;
    }
    __syncthreads();

    // ---- pw dot: wave wv covers cols [wv*32, wv*32+32) ----
    #pragma unroll
    for (int k = 0; k < 4; ++k){
        const unsigned short* src = pw_g + (size_t)(bb*C_ + cc0 + k)*(T_*H_);
        float s8[8];
        #pragma unroll
        for (int e = 0; e < 8; ++e) s8[e] = 0.0f;
        #pragma unroll
        for (int g = 0; g < 4; ++g){
            int col = wv*32 + g*8 + cl;
            short8 pw8 = *(const short8*)&src[col*T_ + t8*8];
            float cv = s_c[k][col];
            #pragma unroll
            for (int e = 0; e < 8; ++e)
                s8[e] = fmaf(cv, bf2f((unsigned short)pw8[e]), s8[e]);
        }
        #pragma unroll
        for (int d = 8; d < 64; d <<= 1)
            #pragma unroll
            for (int e = 0; e < 8; ++e)
                s8[e] += __shfl_xor(s8[e], d, 64);
        if (lane < 8){
            #pragma unroll
            for (int e = 0; e < 8; ++e)
                s_part[k][wv*64 + t8*8 + e] = s8[e];
        }
    }
    __syncthreads();

    {
        int k = tid >> 6, t = tid & 63;
        float s = s_part[k][t] + s_part[k][64+t] + s_part[k][128+t] + s_part[k][192+t];
        int chunk = cc0 + k;
        preds[(size_t)bb*L_ + chunk*T_ + t] =
            s + sloc[(size_t)(bb*C_ + chunk)*T_ + t] + bg[0];
    }
}

extern "C" void kernel_launch(void* const* d_in, const int* in_sizes, int n_in,
                              void* d_out, int out_size, void* d_ws, size_t ws_size,
                              hipStream_t stream){
    const float* x  = (const float*)d_in[0];
    const float* Wp = (const float*)d_in[1];
    const float* bp = (const float*)d_in[2];
    const float* Wz = (const float*)d_in[3];
    const float* bz = (const float*)d_in[4];
    const float* Wh = (const float*)d_in[5];
    const float* bh = (const float*)d_in[6];
    const float* Wg = (const float*)d_in[7];
    const float* bg = (const float*)d_in[8];
    float* preds = (float*)d_out;

    uint8_t* w8 = (uint8_t*)d_ws;
    unsigned short* WzT = (unsigned short*)(w8);
    unsigned short* WhT = (unsigned short*)(w8 + 32768);
    floatx2* agg2 = (floatx2*)(w8 + 65536);                   // 4 MB [bbh][cc]
    float* sloc   = (float*)(w8 + 65536 + 8u*BH_*C_);         // 1 MB
    unsigned short* pw_g = (unsigned short*)(w8 + 65536 + 16u*BH_*C_);  // 64 MB

    hipLaunchKernelGGL(prep_w, dim3(32), dim3(256), 0, stream, Wz, Wh, WzT, WhT);
    hipLaunchKernelGGL(gates_agg, dim3(B_*C_), dim3(256), 0, stream,
                       x, Wp, bp, bz, bh, Wg, WzT, WhT, agg2, sloc, pw_g);
    hipLaunchKernelGGL(apply2, dim3(B_*C_/4), dim3(256), 0, stream,
                       pw_g, agg2, sloc, bg, preds);
}

// Round 16
// 160.104 us; speedup vs baseline: 1.0450x; 1.0450x over previous
//
#include <hip/hip_runtime.h>
#include <hip/hip_bf16.h>
#include <stdint.h>

#define B_   64
#define L_   4096
#define H_   128
#define T_   64
#define C_   (L_/T_)        // 64 chunks per batch row
#define BH_  (B_*H_)        // 8192
#define PADI 136            // bf16 row stride for inp tile

typedef __attribute__((ext_vector_type(8))) short short8;
typedef __attribute__((ext_vector_type(4))) short short4v;
typedef __attribute__((ext_vector_type(4))) float floatx4;
typedef __attribute__((ext_vector_type(2))) float floatx2;

#define LOG2E 1.44269504088896340736f

__device__ __forceinline__ unsigned short f2bf(float f){
    unsigned int u = __float_as_uint(f);
    u += 0x7FFFu + ((u >> 16) & 1u);      // RNE
    return (unsigned short)(u >> 16);
}
__device__ __forceinline__ float bf2f(unsigned short s){
    return __uint_as_float(((unsigned int)s) << 16);
}

// K0: W^T bf16 prep (dense [n][k]) + zero the sloc accumulator; 32 blocks.
__global__ void prep_w(const float* __restrict__ Wz, const float* __restrict__ Wh,
                       unsigned short* __restrict__ WzT, unsigned short* __restrict__ WhT,
                       float* __restrict__ sloc){
    int b = blockIdx.x;
    const float* W = (b < 16) ? Wz : Wh;
    unsigned short* WT = (b < 16) ? WzT : WhT;
    int b16 = b & 15, tid = threadIdx.x;
    #pragma unroll
    for (int it = 0; it < 4; ++it){
        int idx = b16*1024 + it*256 + tid;    // idx = n*128 + k
        int n = idx >> 7, k = idx & 127;
        WT[idx] = f2bf(W[k*H_ + n]);
    }
    // zero sloc: 4096*64 floats over 32 blocks
    float4 z4 = {0.f, 0.f, 0.f, 0.f};
    float4* s4 = (float4*)sloc;
    for (int i = 0; i < 8; ++i)
        s4[b*8192 + i*256 + tid] = z4;
}

// K2: wave-parallel Kogge-Stone scan over the 64 chunk aggregates of each
// (bb,h) row. agg2 layout [bbh][cc] (float2 A,H) -> coalesced 512B wave loads.
__global__ __launch_bounds__(256, 4)
void carry_kogge(const floatx2* __restrict__ agg2, float* __restrict__ carry_g){
    const int row  = blockIdx.x*4 + (threadIdx.x >> 6);   // 8192 rows, 4/block
    const int lane = threadIdx.x & 63;                    // lane = cc
    floatx2 v = agg2[(size_t)row*C_ + lane];
    #pragma unroll
    for (int d = 1; d < 64; d <<= 1){
        float oA = __shfl_up(v[0], d, 64);
        float oH = __shfl_up(v[1], d, 64);
        if (lane >= d){
            v[1] = fmaf(oH, v[0], v[1]);
            v[0] = oA * v[0];
        }
    }
    float eh = __shfl_up(v[1], 1, 64);
    carry_g[(size_t)row*C_ + lane] = (lane == 0) ? 0.0f : eh;
}

// ab LDS layout: row col (0..127) of 256B; 16B chunk t4 at position t4^(col&15).
// Pair (a,b) for t = t4*4+e at ushorts [chunk*8 + 2e, +1]. After the scan the
// pair holds (hw, pw) = (hloc_{t-1}*wg, P(t)*wg) in the same slots.

// Pass 1: r12 compute; LDS trimmed to EXACTLY 32 KB -> 5 blocks/CU.
// Biases/wg read per-thread from global (L1-hot); sloc via atomicAdd.
__global__ __launch_bounds__(256, 5)
void gates_agg(const float* __restrict__ x,
               const float* __restrict__ Wp, const float* __restrict__ bp,
               const float* __restrict__ bz, const float* __restrict__ bh,
               const float* __restrict__ Wg,
               const unsigned short* __restrict__ WzT,
               const unsigned short* __restrict__ WhT,
               floatx2* __restrict__ agg2,
               float* __restrict__ sloc, unsigned short* __restrict__ pw_g)
{
    __shared__ __align__(16) unsigned short s_ab[H_*H_];    // exactly 32768 B
    unsigned short* inp_lds = s_ab;

    const int bid = blockIdx.x;
    const int bb  = bid / C_;
    const int cc  = bid % C_;
    const int t0g = cc * T_;
    const int tid = threadIdx.x;
    const int wv = tid >> 6, lane = tid & 63, quad = lane >> 4, l15 = lane & 15;

    // ---- inp = x @ Wp + bp -> bf16 LDS (A layout [t][k]); Wp/bp hoisted ----
    {
        const int h0 = (tid & 15) * 8;         // iteration-invariant
        float w0[8], w1[8], w2[8], b0[8];
        #pragma unroll
        for (int m = 0; m < 8; ++m){
            w0[m] = Wp[h0+m]; w1[m] = Wp[H_+h0+m]; w2[m] = Wp[2*H_+h0+m];
            b0[m] = bp[h0+m];
        }
        #pragma unroll
        for (int it = 0; it < 4; ++it){
            int t = (tid >> 4) + it*16;
            const float* xr = x + ((size_t)bb*L_ + t0g + t)*3;
            float x0 = xr[0], x1 = xr[1], x2 = xr[2];
            short8 pk;
            #pragma unroll
            for (int m = 0; m < 8; ++m){
                float v = b0[m];
                v = fmaf(x0, w0[m], v);
                v = fmaf(x1, w1[m], v);
                v = fmaf(x2, w2[m], v);
                pk[m] = (short)f2bf(v);
            }
            *(short8*)&inp_lds[t*PADI + h0] = pk;
        }
    }
    __syncthreads();

    const int ct0 = wv*2;

    // ---- fused dual GEMM: Sz/Sh = inp @ {Wz,Wh}^T, A-frags read once ----
    floatx4 accz[4][2], acch[4][2];
    #pragma unroll
    for (int r = 0; r < 4; ++r)
        #pragma unroll
        for (int c = 0; c < 2; ++c){
            accz[r][c] = (floatx4){0.f,0.f,0.f,0.f};
            acch[r][c] = (floatx4){0.f,0.f,0.f,0.f};
        }
    #pragma unroll
    for (int kk = 0; kk < 4; ++kk){
        short8 af[4], bz_[2], bh_[2];
        #pragma unroll
        for (int r = 0; r < 4; ++r)
            af[r] = *(const short8*)&inp_lds[(r*16 + l15)*PADI + kk*32 + quad*8];
        #pragma unroll
        for (int c = 0; c < 2; ++c){
            bz_[c] = *(const short8*)&WzT[((ct0+c)*16 + l15)*H_ + kk*32 + quad*8];
            bh_[c] = *(const short8*)&WhT[((ct0+c)*16 + l15)*H_ + kk*32 + quad*8];
        }
        #pragma unroll
        for (int r = 0; r < 4; ++r)
            #pragma unroll
            for (int c = 0; c < 2; ++c){
                accz[r][c] = __builtin_amdgcn_mfma_f32_16x16x32_bf16(af[r], bz_[c], accz[r][c], 0, 0, 0);
                acch[r][c] = __builtin_amdgcn_mfma_f32_16x16x32_bf16(af[r], bh_[c], acch[r][c], 0, 0, 0);
            }
    }
    __syncthreads();   // inp reads done before ab overlay

    // ---- trimmed epilogue: a = sigmoid(-sz); b = (1-a)*tanh(sh) ----
    // biases direct from global: 2 cols/thread, 1 KB shared by all blocks (L1/L2).
    {
        float vbz[2], vbh[2];
        #pragma unroll
        for (int c = 0; c < 2; ++c){
            int col = (ct0+c)*16 + l15;
            vbz[c] = bz[col]; vbh[c] = bh[col];
        }
        #pragma unroll
        for (int r = 0; r < 4; ++r){
            #pragma unroll
            for (int c = 0; c < 2; ++c){
                int col = (ct0+c)*16 + l15;
                short8 pk;
                #pragma unroll
                for (int e = 0; e < 4; ++e){
                    float szb = accz[r][c][e] + vbz[c];
                    float a = __builtin_amdgcn_rcpf(1.0f + __builtin_amdgcn_exp2f(szb * LOG2E));
                    float shb = acch[r][c][e] + vbh[c];
                    float ex = __builtin_amdgcn_exp2f(2.0f*LOG2E*shb);
                    float th = 1.0f - 2.0f*__builtin_amdgcn_rcpf(ex + 1.0f);
                    float bt = (1.0f - a) * th;
                    pk[2*e]   = (short)f2bf(a);
                    pk[2*e+1] = (short)f2bf(bt);
                }
                int ch = (r*4 + quad) ^ l15;
                *(short8*)&s_ab[col*H_ + ch*8] = pk;
            }
        }
    }
    __syncthreads();

    // ---- LDS-only in-place scan: (a,b) -> (hw,pw); agg out (float2) ----
    if (tid < H_){
        float A = 1.0f, h = 0.0f;
        float wgv = Wg[tid];               // L1-hot
        #pragma unroll
        for (int t4 = 0; t4 < 16; ++t4){
            int base = tid*H_ + ((t4 ^ (tid & 15)) << 3);
            short8 pr = *(const short8*)&s_ab[base];
            short8 wb;
            #pragma unroll
            for (int e = 0; e < 4; ++e){
                float aa = bf2f((unsigned short)pr[2*e]);
                float bv = bf2f((unsigned short)pr[2*e+1]);
                wb[2*e]   = (short)f2bf(h * wgv);   // hloc_{t-1} * wg
                wb[2*e+1] = (short)f2bf(A * wgv);   // P(t) * wg
                A *= aa;
                h = fmaf(aa, h, bv);
            }
            *(short8*)&s_ab[base] = wb;             // in-place, same banks
        }
        agg2[(size_t)(bb*H_ + tid)*C_ + cc] = (floatx2){A, h};
    }
    __syncthreads();

    // ---- coalesced pw dump: deinterleave to [col][t], all 256 threads ----
    {
        unsigned short* dst = pw_g + (size_t)bid*(T_*H_);
        #pragma unroll
        for (int i = 0; i < 8; ++i){
            int idx = i*256 + tid;                 // (col, t4)
            int col = idx >> 4, t4 = idx & 15;
            short8 pr = *(const short8*)&s_ab[col*H_ + ((t4 ^ (col & 15)) << 3)];
            short4v pw4;
            pw4[0] = pr[1]; pw4[1] = pr[3]; pw4[2] = pr[5]; pw4[3] = pr[7];
            *(short4v*)&dst[col*T_ + t4*4] = pw4;  // consecutive 8B per thread
        }
    }

    // ---- sloc reduction: per-wave partial + one atomicAdd per (wave,t) ----
    {
        int t = tid & 63, w4 = tid >> 6;
        int t4 = t >> 2, e2 = (t & 3)*2;
        float s = 0.0f;
        #pragma unroll
        for (int j = 0; j < 32; ++j){
            int col = w4*32 + j;
            s += bf2f(s_ab[col*H_ + ((t4 ^ (col & 15)) << 3) + e2]);
        }
        atomicAdd(&sloc[(size_t)bid*T_ + t], s);   // 4 adds/address, pre-zeroed
    }
}

// Pass 2 (r12 proven): 4 chunks per block; carry staged once; wide pw loads.
__global__ __launch_bounds__(256, 4)
void apply2(const unsigned short* __restrict__ pw_g,
            const float* __restrict__ carry_g,
            const float* __restrict__ sloc, const float* __restrict__ bg,
            float* __restrict__ preds)
{
    __shared__ float s_c[4][H_];
    __shared__ float s_part[4][256];
    const int bid = blockIdx.x;          // 1024 blocks
    const int bb  = bid >> 4;
    const int cc0 = (bid & 15) * 4;
    const int tid = threadIdx.x;
    const int wv = tid >> 6, lane = tid & 63;
    const int cl = lane >> 3, t8 = lane & 7;

    #pragma unroll
    for (int i = 0; i < 2; ++i){
        int idx = tid + i*256;           // (h, k)
        int k = idx & 3, h = idx >> 2;
        s_c[k][h] = carry_g[(size_t)(bb*H_ + h)*C_ + cc0 + k];
    }
    __syncthreads();

    #pragma unroll
    for (int k = 0; k < 4; ++k){
        const unsigned short* src = pw_g + (size_t)(bb*C_ + cc0 + k)*(T_*H_);
        float s8[8];
        #pragma unroll
        for (int e = 0; e < 8; ++e) s8[e] = 0.0f;
        #pragma unroll
        for (int g = 0; g < 4; ++g){
            int col = wv*32 + g*8 + cl;
            short8 pw8 = *(const short8*)&src[col*T_ + t8*8];
            float cv = s_c[k][col];
            #pragma unroll
            for (int e = 0; e < 8; ++e)
                s8[e] = fmaf(cv, bf2f((unsigned short)pw8[e]), s8[e]);
        }
        #pragma unroll
        for (int d = 8; d < 64; d <<= 1)
            #pragma unroll
            for (int e = 0; e < 8; ++e)
                s8[e] += __shfl_xor(s8[e], d, 64);
        if (lane < 8){
            #pragma unroll
            for (int e = 0; e < 8; ++e)
                s_part[k][wv*64 + t8*8 + e] = s8[e];
        }
    }
    __syncthreads();

    {
        int k = tid >> 6, t = tid & 63;
        float s = s_part[k][t] + s_part[k][64+t] + s_part[k][128+t] + s_part[k][192+t];
        int chunk = cc0 + k;
        preds[(size_t)bb*L_ + chunk*T_ + t] =
            s + sloc[(size_t)(bb*C_ + chunk)*T_ + t] + bg[0];
    }
}

extern "C" void kernel_launch(void* const* d_in, const int* in_sizes, int n_in,
                              void* d_out, int out_size, void* d_ws, size_t ws_size,
                              hipStream_t stream){
    const float* x  = (const float*)d_in[0];
    const float* Wp = (const float*)d_in[1];
    const float* bp = (const float*)d_in[2];
    const float* Wz = (const float*)d_in[3];
    const float* bz = (const float*)d_in[4];
    const float* Wh = (const float*)d_in[5];
    const float* bh = (const float*)d_in[6];
    const float* Wg = (const float*)d_in[7];
    const float* bg = (const float*)d_in[8];
    float* preds = (float*)d_out;

    uint8_t* w8 = (uint8_t*)d_ws;
    unsigned short* WzT = (unsigned short*)(w8);
    unsigned short* WhT = (unsigned short*)(w8 + 32768);
    floatx2* agg2 = (floatx2*)(w8 + 65536);                   // 4 MB [bbh][cc]
    float* sloc   = (float*)(w8 + 65536 + 8u*BH_*C_);         // 1 MB
    float* carry  = (float*)(w8 + 65536 + 12u*BH_*C_);        // 2 MB [bbh][cc]
    unsigned short* pw_g = (unsigned short*)(w8 + 65536 + 16u*BH_*C_);  // 64 MB

    hipLaunchKernelGGL(prep_w, dim3(32), dim3(256), 0, stream, Wz, Wh, WzT, WhT, sloc);
    hipLaunchKernelGGL(gates_agg, dim3(B_*C_), dim3(256), 0, stream,
                       x, Wp, bp, bz, bh, Wg, WzT, WhT, agg2, sloc, pw_g);
    hipLaunchKernelGGL(carry_kogge, dim3(BH_/4), dim3(256), 0, stream, agg2, carry);
    hipLaunchKernelGGL(apply2, dim3(B_*C_/4), dim3(256), 0, stream,
                       pw_g, carry, sloc, bg, preds);
}

// Round 17
// 154.608 us; speedup vs baseline: 1.0822x; 1.0355x over previous
//
#include <hip/hip_runtime.h>
#include <hip/hip_bf16.h>
#include <stdint.h>

#define B_   64
#define L_   4096
#define H_   128
#define T_   64
#define C_   (L_/T_)        // 64 chunks per batch row
#define BH_  (B_*H_)        // 8192
#define PADI 136            // bf16 row stride for inp tile

typedef __attribute__((ext_vector_type(8))) short short8;
typedef __attribute__((ext_vector_type(4))) short short4v;
typedef __attribute__((ext_vector_type(4))) float floatx4;
typedef __attribute__((ext_vector_type(2))) float floatx2;

#define LOG2E 1.44269504088896340736f

__device__ __forceinline__ unsigned short f2bf(float f){
    unsigned int u = __float_as_uint(f);
    u += 0x7FFFu + ((u >> 16) & 1u);      // RNE
    return (unsigned short)(u >> 16);
}
__device__ __forceinline__ float bf2f(unsigned short s){
    return __uint_as_float(((unsigned int)s) << 16);
}

// K0: W^T bf16 prep (dense [n][k]); 32 blocks.
__global__ void prep_w(const float* __restrict__ Wz, const float* __restrict__ Wh,
                       unsigned short* __restrict__ WzT, unsigned short* __restrict__ WhT){
    int b = blockIdx.x;
    const float* W = (b < 16) ? Wz : Wh;
    unsigned short* WT = (b < 16) ? WzT : WhT;
    int b16 = b & 15, tid = threadIdx.x;
    #pragma unroll
    for (int it = 0; it < 4; ++it){
        int idx = b16*1024 + it*256 + tid;    // idx = n*128 + k
        int n = idx >> 7, k = idx & 127;
        WT[idx] = f2bf(W[k*H_ + n]);
    }
}

// K2: wave-parallel Kogge-Stone scan over the 64 chunk aggregates of each
// (bb,h) row. agg2 layout [bbh][cc] (float2 A,H) -> coalesced 512B wave loads.
__global__ __launch_bounds__(256, 4)
void carry_kogge(const floatx2* __restrict__ agg2, float* __restrict__ carry_g){
    const int row  = blockIdx.x*4 + (threadIdx.x >> 6);   // 8192 rows, 4/block
    const int lane = threadIdx.x & 63;                    // lane = cc
    floatx2 v = agg2[(size_t)row*C_ + lane];
    #pragma unroll
    for (int d = 1; d < 64; d <<= 1){
        float oA = __shfl_up(v[0], d, 64);
        float oH = __shfl_up(v[1], d, 64);
        if (lane >= d){
            v[1] = fmaf(oH, v[0], v[1]);
            v[0] = oA * v[0];
        }
    }
    float eh = __shfl_up(v[1], 1, 64);
    carry_g[(size_t)row*C_ + lane] = (lane == 0) ? 0.0f : eh;
}

// ab LDS layout: row col (0..127) of 256B; 16B chunk t4 at position t4^(col&15).
// Pair (a,b) for t = t4*4+e at ushorts [chunk*8 + 2e, +1]. After the scan the
// pair holds (hw, pw) = (hloc_{t-1}*wg, P(t)*wg) in the same slots.

// Pass 1 (exact r12 best): inp + fused dual GEMM + trimmed gate epilogue +
// LDS in-place scan + coalesced pw dump + conflict-free sloc reduction.
__global__ __launch_bounds__(256, 4)
void gates_agg(const float* __restrict__ x,
               const float* __restrict__ Wp, const float* __restrict__ bp,
               const float* __restrict__ bz, const float* __restrict__ bh,
               const float* __restrict__ Wg,
               const unsigned short* __restrict__ WzT,
               const unsigned short* __restrict__ WhT,
               floatx2* __restrict__ agg2,
               float* __restrict__ sloc, unsigned short* __restrict__ pw_g)
{
    __shared__ __align__(16) unsigned short s_ab[H_*H_];    // 32 KB (inp overlays)
    __shared__ float s_bz[H_], s_bh[H_], s_wg[H_];
    __shared__ float s_part[256];
    unsigned short* inp_lds = s_ab;

    const int bid = blockIdx.x;
    const int bb  = bid / C_;
    const int cc  = bid % C_;
    const int t0g = cc * T_;
    const int tid = threadIdx.x;
    const int wv = tid >> 6, lane = tid & 63, quad = lane >> 4, l15 = lane & 15;

    if (tid < H_){ s_bz[tid] = bz[tid]; s_bh[tid] = bh[tid]; s_wg[tid] = Wg[tid]; }

    // ---- inp = x @ Wp + bp -> bf16 LDS (A layout [t][k]); Wp/bp hoisted ----
    {
        const int h0 = (tid & 15) * 8;         // iteration-invariant
        float w0[8], w1[8], w2[8], b0[8];
        #pragma unroll
        for (int m = 0; m < 8; ++m){
            w0[m] = Wp[h0+m]; w1[m] = Wp[H_+h0+m]; w2[m] = Wp[2*H_+h0+m];
            b0[m] = bp[h0+m];
        }
        #pragma unroll
        for (int it = 0; it < 4; ++it){
            int t = (tid >> 4) + it*16;
            const float* xr = x + ((size_t)bb*L_ + t0g + t)*3;
            float x0 = xr[0], x1 = xr[1], x2 = xr[2];
            short8 pk;
            #pragma unroll
            for (int m = 0; m < 8; ++m){
                float v = b0[m];
                v = fmaf(x0, w0[m], v);
                v = fmaf(x1, w1[m], v);
                v = fmaf(x2, w2[m], v);
                pk[m] = (short)f2bf(v);
            }
            *(short8*)&inp_lds[t*PADI + h0] = pk;
        }
    }
    __syncthreads();

    const int ct0 = wv*2;

    // ---- fused dual GEMM: Sz/Sh = inp @ {Wz,Wh}^T, A-frags read once ----
    floatx4 accz[4][2], acch[4][2];
    #pragma unroll
    for (int r = 0; r < 4; ++r)
        #pragma unroll
        for (int c = 0; c < 2; ++c){
            accz[r][c] = (floatx4){0.f,0.f,0.f,0.f};
            acch[r][c] = (floatx4){0.f,0.f,0.f,0.f};
        }
    #pragma unroll
    for (int kk = 0; kk < 4; ++kk){
        short8 af[4], bz_[2], bh_[2];
        #pragma unroll
        for (int r = 0; r < 4; ++r)
            af[r] = *(const short8*)&inp_lds[(r*16 + l15)*PADI + kk*32 + quad*8];
        #pragma unroll
        for (int c = 0; c < 2; ++c){
            bz_[c] = *(const short8*)&WzT[((ct0+c)*16 + l15)*H_ + kk*32 + quad*8];
            bh_[c] = *(const short8*)&WhT[((ct0+c)*16 + l15)*H_ + kk*32 + quad*8];
        }
        #pragma unroll
        for (int r = 0; r < 4; ++r)
            #pragma unroll
            for (int c = 0; c < 2; ++c){
                accz[r][c] = __builtin_amdgcn_mfma_f32_16x16x32_bf16(af[r], bz_[c], accz[r][c], 0, 0, 0);
                acch[r][c] = __builtin_amdgcn_mfma_f32_16x16x32_bf16(af[r], bh_[c], acch[r][c], 0, 0, 0);
            }
    }
    __syncthreads();   // inp reads done before ab overlay

    // ---- trimmed epilogue: a = sigmoid(-sz); b = (1-a)*tanh(sh) ----
    #pragma unroll
    for (int r = 0; r < 4; ++r){
        #pragma unroll
        for (int c = 0; c < 2; ++c){
            int col = (ct0+c)*16 + l15;
            float vbz = s_bz[col], vbh = s_bh[col];
            short8 pk;
            #pragma unroll
            for (int e = 0; e < 4; ++e){
                float szb = accz[r][c][e] + vbz;
                float a = __builtin_amdgcn_rcpf(1.0f + __builtin_amdgcn_exp2f(szb * LOG2E));
                float shb = acch[r][c][e] + vbh;
                float ex = __builtin_amdgcn_exp2f(2.0f*LOG2E*shb);
                float th = 1.0f - 2.0f*__builtin_amdgcn_rcpf(ex + 1.0f);
                float bt = (1.0f - a) * th;
                pk[2*e]   = (short)f2bf(a);
                pk[2*e+1] = (short)f2bf(bt);
            }
            int ch = (r*4 + quad) ^ l15;
            *(short8*)&s_ab[col*H_ + ch*8] = pk;
        }
    }
    __syncthreads();

    // ---- LDS-only in-place scan: (a,b) -> (hw,pw); agg out (float2) ----
    if (tid < H_){
        float A = 1.0f, h = 0.0f;
        float wgv = s_wg[tid];
        #pragma unroll
        for (int t4 = 0; t4 < 16; ++t4){
            int base = tid*H_ + ((t4 ^ (tid & 15)) << 3);
            short8 pr = *(const short8*)&s_ab[base];
            short8 wb;
            #pragma unroll
            for (int e = 0; e < 4; ++e){
                float aa = bf2f((unsigned short)pr[2*e]);
                float bv = bf2f((unsigned short)pr[2*e+1]);
                wb[2*e]   = (short)f2bf(h * wgv);   // hloc_{t-1} * wg
                wb[2*e+1] = (short)f2bf(A * wgv);   // P(t) * wg
                A *= aa;
                h = fmaf(aa, h, bv);
            }
            *(short8*)&s_ab[base] = wb;             // in-place, same banks
        }
        agg2[(size_t)(bb*H_ + tid)*C_ + cc] = (floatx2){A, h};
    }
    __syncthreads();

    // ---- coalesced pw dump: deinterleave to [col][t], all 256 threads ----
    {
        unsigned short* dst = pw_g + (size_t)bid*(T_*H_);
        #pragma unroll
        for (int i = 0; i < 8; ++i){
            int idx = i*256 + tid;                 // (col, t4)
            int col = idx >> 4, t4 = idx & 15;
            short8 pr = *(const short8*)&s_ab[col*H_ + ((t4 ^ (col & 15)) << 3)];
            short4v pw4;
            pw4[0] = pr[1]; pw4[1] = pr[3]; pw4[2] = pr[5]; pw4[3] = pr[7];
            *(short4v*)&dst[col*T_ + t4*4] = pw4;  // consecutive 8B per thread
        }
    }

    // ---- sloc reduction, conflict-free (lane index = t) ----
    {
        int t = tid & 63, w4 = tid >> 6;
        int t4 = t >> 2, e2 = (t & 3)*2;
        float s = 0.0f;
        #pragma unroll
        for (int j = 0; j < 32; ++j){
            int col = w4*32 + j;
            s += bf2f(s_ab[col*H_ + ((t4 ^ (col & 15)) << 3) + e2]);
        }
        s_part[w4*64 + t] = s;
    }
    __syncthreads();
    if (tid < 64)
        sloc[(size_t)bid*T_ + tid] =
            s_part[tid] + s_part[64+tid] + s_part[128+tid] + s_part[192+tid];
}

// Pass 2: XCD-aligned chunk grouping. gates_agg block bb*64+cc lands on XCD
// cc%8 (round-robin dispatch), so chunk cc's pw tile is hot in that XCD's L2.
// Group chunks {c4, c4+16, c4+32, c4+48} (all == c4 mod 16): this block
// (bid = bb*16+c4 -> XCD c4%8) reads only pw written by its own XCD.
__global__ __launch_bounds__(256, 4)
void apply2(const unsigned short* __restrict__ pw_g,
            const float* __restrict__ carry_g,
            const float* __restrict__ sloc, const float* __restrict__ bg,
            float* __restrict__ preds)
{
    __shared__ float s_c[4][H_];
    __shared__ float s_part[4][256];
    const int bid = blockIdx.x;          // 1024 blocks
    const int bb  = bid >> 4;
    const int c4  = bid & 15;            // chunk k = c4 + 16*k
    const int tid = threadIdx.x;
    const int wv = tid >> 6, lane = tid & 63;
    const int cl = lane >> 3, t8 = lane & 7;

    // stage 4 carry vectors (strided chunks)
    #pragma unroll
    for (int i = 0; i < 2; ++i){
        int idx = tid + i*256;           // (h, k)
        int k = idx & 3, h = idx >> 2;
        s_c[k][h] = carry_g[(size_t)(bb*H_ + h)*C_ + c4 + 16*k];
    }
    __syncthreads();

    #pragma unroll
    for (int k = 0; k < 4; ++k){
        const int chunk = c4 + 16*k;
        const unsigned short* src = pw_g + (size_t)(bb*C_ + chunk)*(T_*H_);
        float s8[8];
        #pragma unroll
        for (int e = 0; e < 8; ++e) s8[e] = 0.0f;
        #pragma unroll
        for (int g = 0; g < 4; ++g){
            int col = wv*32 + g*8 + cl;
            short8 pw8 = *(const short8*)&src[col*T_ + t8*8];
            float cv = s_c[k][col];
            #pragma unroll
            for (int e = 0; e < 8; ++e)
                s8[e] = fmaf(cv, bf2f((unsigned short)pw8[e]), s8[e]);
        }
        #pragma unroll
        for (int d = 8; d < 64; d <<= 1)
            #pragma unroll
            for (int e = 0; e < 8; ++e)
                s8[e] += __shfl_xor(s8[e], d, 64);
        if (lane < 8){
            #pragma unroll
            for (int e = 0; e < 8; ++e)
                s_part[k][wv*64 + t8*8 + e] = s8[e];
        }
    }
    __syncthreads();

    {
        int k = tid >> 6, t = tid & 63;
        float s = s_part[k][t] + s_part[k][64+t] + s_part[k][128+t] + s_part[k][192+t];
        int chunk = c4 + 16*k;
        preds[(size_t)bb*L_ + chunk*T_ + t] =
            s + sloc[(size_t)(bb*C_ + chunk)*T_ + t] + bg[0];
    }
}

extern "C" void kernel_launch(void* const* d_in, const int* in_sizes, int n_in,
                              void* d_out, int out_size, void* d_ws, size_t ws_size,
                              hipStream_t stream){
    const float* x  = (const float*)d_in[0];
    const float* Wp = (const float*)d_in[1];
    const float* bp = (const float*)d_in[2];
    const float* Wz = (const float*)d_in[3];
    const float* bz = (const float*)d_in[4];
    const float* Wh = (const float*)d_in[5];
    const float* bh = (const float*)d_in[6];
    const float* Wg = (const float*)d_in[7];
    const float* bg = (const float*)d_in[8];
    float* preds = (float*)d_out;

    uint8_t* w8 = (uint8_t*)d_ws;
    unsigned short* WzT = (unsigned short*)(w8);
    unsigned short* WhT = (unsigned short*)(w8 + 32768);
    floatx2* agg2 = (floatx2*)(w8 + 65536);                   // 4 MB [bbh][cc]
    float* sloc   = (float*)(w8 + 65536 + 8u*BH_*C_);         // 1 MB
    float* carry  = (float*)(w8 + 65536 + 12u*BH_*C_);        // 2 MB [bbh][cc]
    unsigned short* pw_g = (unsigned short*)(w8 + 65536 + 16u*BH_*C_);  // 64 MB

    hipLaunchKernelGGL(prep_w, dim3(32), dim3(256), 0, stream, Wz, Wh, WzT, WhT);
    hipLaunchKernelGGL(gates_agg, dim3(B_*C_), dim3(256), 0, stream,
                       x, Wp, bp, bz, bh, Wg, WzT, WhT, agg2, sloc, pw_g);
    hipLaunchKernelGGL(carry_kogge, dim3(BH_/4), dim3(256), 0, stream, agg2, carry);
    hipLaunchKernelGGL(apply2, dim3(B_*C_/4), dim3(256), 0, stream,
                       pw_g, carry, sloc, bg, preds);
}